// Round 14
// baseline (314.607 us; speedup 1.0000x reference)
//
#include <hip/hip_runtime.h>
#include <cstdint>
#include <cstddef>

#define NTOK 4096
#define DMODEL 1024
#define NHEAD 8
#define DHEAD 128
#define DFFN 1536
#define LNEPS 1e-5f

typedef __bf16 bf16_t;
typedef __bf16 bf16x8 __attribute__((ext_vector_type(8)));
typedef __bf16 bf16x4 __attribute__((ext_vector_type(4)));
typedef float f32x4 __attribute__((ext_vector_type(4)));
typedef float f32x16 __attribute__((ext_vector_type(16)));

__device__ __forceinline__ void gload_lds16(const bf16_t* g, bf16_t* lds) {
  __builtin_amdgcn_global_load_lds(
      (const __attribute__((address_space(1))) unsigned int*)g,
      (__attribute__((address_space(3))) unsigned int*)lds, 16, 0, 0);
}

// raw-ISA math (single instruction each; ~1ulp, fine for bf16 outputs)
__device__ __forceinline__ float fexp2(float x) {
  float r;
  asm("v_exp_f32 %0, %1" : "=v"(r) : "v"(x));
  return r;
}
__device__ __forceinline__ float fsqrt(float x) {
  float r;
  asm("v_sqrt_f32 %0, %1" : "=v"(r) : "v"(x));
  return r;
}
__device__ __forceinline__ unsigned cvtpk(float lo, float hi) {
  unsigned r;
  asm("v_cvt_pk_bf16_f32 %0, %1, %2" : "=v"(r) : "v"(lo), "v"(hi));
  return r;
}

// ---------------- mega convert: all weights + features + coords, 1 launch ----------------
#define CVT_TOTAL 2885632
__global__ __launch_bounds__(256) void cvt_all(
    const float* __restrict__ f, const float* __restrict__ wq,
    const float* __restrict__ wk, const float* __restrict__ wv,
    const float* __restrict__ wo, const float* __restrict__ w1,
    const float* __restrict__ w2, const int* __restrict__ coords,
    bf16_t* __restrict__ fb, bf16_t* __restrict__ wqkv,
    bf16_t* __restrict__ wob, bf16_t* __restrict__ w1b,
    bf16_t* __restrict__ w2b, float2* __restrict__ cfl)
{
  for (int u = blockIdx.x * 256 + threadIdx.x; u < CVT_TOTAL; u += 2048 * 256) {
    if (u < 2048) {
      int4 c = reinterpret_cast<const int4*>(coords)[u];
      float4 o;
      o.x = (float)c.x; o.y = (float)c.y; o.z = (float)c.z; o.w = (float)c.w;
      reinterpret_cast<float4*>(cfl)[u] = o;
      continue;
    }
    int v = u - 2048;
    const float* src; bf16_t* dst; int base;
    if (v < 1048576)      { src = f;  dst = fb;            base = 0; }
    else if (v < 1310720) { src = wq; dst = wqkv;          base = 1048576; }
    else if (v < 1572864) { src = wk; dst = wqkv + 1048576; base = 1310720; }
    else if (v < 1835008) { src = wv; dst = wqkv + 2097152; base = 1572864; }
    else if (v < 2097152) { src = wo; dst = wob;           base = 1835008; }
    else if (v < 2490368) { src = w1; dst = w1b;           base = 2097152; }
    else                  { src = w2; dst = w2b;           base = 2490368; }
    int local = v - base;
    const float4 x = reinterpret_cast<const float4*>(src)[local];
    bf16x4 o = {(bf16_t)x.x, (bf16_t)x.y, (bf16_t)x.z, (bf16_t)x.w};
    reinterpret_cast<bf16x4*>(dst)[local] = o;
  }
}

// ---------------- bf16 GEMM, C = A @ B^T, 64x128 tile, LDS dbuf ----------------
template<int EPI>
__global__ __launch_bounds__(256) void gemm_bt(
    const bf16_t* __restrict__ A, const bf16_t* __restrict__ B,
    int M, int Nn, int K,
    const float* __restrict__ bias, const float* __restrict__ resid,
    const bf16_t* __restrict__ residH,
    float* __restrict__ outF, bf16_t* __restrict__ outH)
{
  __shared__ bf16_t As[2][64 * 32];
  __shared__ bf16_t Bs[2][128 * 32];
  const int t = threadIdx.x;
  const int w = t >> 6, l = t & 63;
  const int lg = l >> 4, li = l & 15;
  const int m0 = blockIdx.x * 64, n0 = blockIdx.y * 128;
  const int wr = (w >> 1) * 32, wc = (w & 1) * 64;
  const f32x4 fz = {0.f, 0.f, 0.f, 0.f};
  f32x4 acc[2][4];
#pragma unroll
  for (int i = 0; i < 2; i++)
#pragma unroll
    for (int j = 0; j < 4; j++) acc[i][j] = fz;

  const bf16_t* Ag = A + (size_t)m0 * K;
  const bf16_t* Bg = B + (size_t)n0 * K;
  const int ca = w * 64 + l;
  const int nK = K >> 5;

  gload_lds16(Ag + (size_t)(ca >> 2) * K + (ca & 3) * 8, &As[0][(w * 64) * 8]);
#pragma unroll
  for (int p = 0; p < 2; p++) {
    int cb = p * 256 + ca;
    gload_lds16(Bg + (size_t)(cb >> 2) * K + (cb & 3) * 8, &Bs[0][(p * 256 + w * 64) * 8]);
  }
  __syncthreads();

  for (int ki = 0; ki < nK; ki++) {
    const int cur = ki & 1;
    if (ki + 1 < nK) {
      const int kt = (ki + 1) << 5;
      gload_lds16(Ag + (size_t)(ca >> 2) * K + kt + (ca & 3) * 8,
                  &As[cur ^ 1][(w * 64) * 8]);
#pragma unroll
      for (int p = 0; p < 2; p++) {
        int cb = p * 256 + ca;
        gload_lds16(Bg + (size_t)(cb >> 2) * K + kt + (cb & 3) * 8,
                    &Bs[cur ^ 1][(p * 256 + w * 64) * 8]);
      }
    }
    bf16x8 af[2], bfr[4];
#pragma unroll
    for (int mi = 0; mi < 2; mi++)
      af[mi] = *reinterpret_cast<const bf16x8*>(&As[cur][(wr + mi * 16 + li) * 32 + lg * 8]);
#pragma unroll
    for (int ni = 0; ni < 4; ni++)
      bfr[ni] = *reinterpret_cast<const bf16x8*>(&Bs[cur][(wc + ni * 16 + li) * 32 + lg * 8]);
#pragma unroll
    for (int mi = 0; mi < 2; mi++)
#pragma unroll
      for (int ni = 0; ni < 4; ni++)
        acc[mi][ni] = __builtin_amdgcn_mfma_f32_16x16x32_bf16(af[mi], bfr[ni], acc[mi][ni], 0, 0, 0);
    __syncthreads();
  }

#pragma unroll
  for (int mi = 0; mi < 2; mi++) {
#pragma unroll
    for (int ni = 0; ni < 4; ni++) {
      int gcol = n0 + wc + ni * 16 + li;
#pragma unroll
      for (int r = 0; r < 4; r++) {
        int grow = m0 + wr + mi * 16 + lg * 4 + r;
        float v = acc[mi][ni][r];
        if (EPI == 0) {
          outH[(size_t)grow * Nn + gcol] = (bf16_t)v;
        } else if (EPI == 1) {
          v += bias[gcol] + resid[(size_t)grow * Nn + gcol];
          outF[(size_t)grow * Nn + gcol] = v;
        } else if (EPI == 2) {
          v += bias[gcol];
          v = 0.5f * v * (1.f + erff(v * 0.70710678118654752f));
          outH[(size_t)grow * Nn + gcol] = (bf16_t)v;
        } else {
          v += bias[gcol] + (float)residH[(size_t)grow * Nn + gcol];
          outF[(size_t)grow * Nn + gcol] = v;
        }
      }
    }
  }
}

// ---------------- fused QKV GEMM: 128x128 tile (m97-class), dbuf, scatter epi ----------------
// Grid (4096/128, 3072/128) = 32 x 24 = 768 blocks (3/CU). 4 waves, acc 4x4.
__global__ __launch_bounds__(256) void gemm_qkv(
    const bf16_t* __restrict__ A, const bf16_t* __restrict__ B,
    bf16_t* __restrict__ Qo, bf16_t* __restrict__ Kp, bf16_t* __restrict__ Vp)
{
  const int K = DMODEL;
  __shared__ bf16_t As[2][128 * 32];
  __shared__ bf16_t Bs[2][128 * 32];
  const int t = threadIdx.x;
  const int w = t >> 6, l = t & 63;
  const int lg = l >> 4, li = l & 15;
  const int m0 = blockIdx.x * 128, n0 = blockIdx.y * 128;
  const int wr = (w >> 1) * 64, wc = (w & 1) * 64;
  const f32x4 fz = {0.f, 0.f, 0.f, 0.f};
  f32x4 acc[4][4];
#pragma unroll
  for (int i = 0; i < 4; i++)
#pragma unroll
    for (int j = 0; j < 4; j++) acc[i][j] = fz;

  const bf16_t* Ag = A + (size_t)m0 * K;
  const bf16_t* Bg = B + (size_t)n0 * K;
  const int nK = K >> 5;

#pragma unroll
  for (int p = 0; p < 2; p++) {
    int c = p * 256 + w * 64 + l;
    gload_lds16(Ag + (size_t)(c >> 2) * K + (c & 3) * 8, &As[0][(p * 256 + w * 64) * 8]);
    gload_lds16(Bg + (size_t)(c >> 2) * K + (c & 3) * 8, &Bs[0][(p * 256 + w * 64) * 8]);
  }
  __syncthreads();

  for (int ki = 0; ki < nK; ki++) {
    const int cur = ki & 1;
    if (ki + 1 < nK) {
      const int kt = (ki + 1) << 5;
#pragma unroll
      for (int p = 0; p < 2; p++) {
        int c = p * 256 + w * 64 + l;
        gload_lds16(Ag + (size_t)(c >> 2) * K + kt + (c & 3) * 8,
                    &As[cur ^ 1][(p * 256 + w * 64) * 8]);
        gload_lds16(Bg + (size_t)(c >> 2) * K + kt + (c & 3) * 8,
                    &Bs[cur ^ 1][(p * 256 + w * 64) * 8]);
      }
    }
    bf16x8 af[4], bfr[4];
#pragma unroll
    for (int mi = 0; mi < 4; mi++)
      af[mi] = *reinterpret_cast<const bf16x8*>(&As[cur][(wr + mi * 16 + li) * 32 + lg * 8]);
#pragma unroll
    for (int ni = 0; ni < 4; ni++)
      bfr[ni] = *reinterpret_cast<const bf16x8*>(&Bs[cur][(wc + ni * 16 + li) * 32 + lg * 8]);
#pragma unroll
    for (int mi = 0; mi < 4; mi++)
#pragma unroll
      for (int ni = 0; ni < 4; ni++)
        acc[mi][ni] = __builtin_amdgcn_mfma_f32_16x16x32_bf16(af[mi], bfr[ni], acc[mi][ni], 0, 0, 0);
    __syncthreads();
  }

  const int region = n0 >> 10;   // block-uniform: 0=Q, 1=K, 2=V
#pragma unroll
  for (int mi = 0; mi < 4; mi++) {
#pragma unroll
    for (int ni = 0; ni < 4; ni++) {
      int gcol = n0 + wc + ni * 16 + li;
#pragma unroll
      for (int r = 0; r < 4; r++) {
        int token = m0 + wr + mi * 16 + lg * 4 + r;
        bf16_t v = (bf16_t)acc[mi][ni][r];
        if (region == 0) {
          Qo[(size_t)token * DMODEL + gcol] = v;
        } else if (region == 1) {
          int gc = gcol - 1024;
          int h = gc >> 7, d = gc & 127;
          size_t addr = ((size_t)(h * 128 + (token >> 5))) * 4096 +
                        (d >> 4) * 512 + ((d >> 3) & 1) * 256 + (token & 31) * 8 + (d & 7);
          Kp[addr] = v;
        } else {
          int gc = gcol - 2048;
          int h = gc >> 7, dh = gc & 127;
          size_t addr = ((size_t)(h * 128 + (token >> 5))) * 4096 +
                        (((token >> 4) & 1) * 4 + (dh >> 5)) * 512 +
                        ((token >> 3) & 1) * 256 + (dh & 31) * 8 + (token & 7);
          Vp[addr] = v;
        }
      }
    }
  }
}

// ---------------- fused dual-softmax flash attention, v10 ----------------
// v9 + v_permlane32_swap_b32 replacing 16 shfl_xor DS-ops + 16 selects on
// the softmax->PV critical path (T12 primitive), + s_setprio(1) around both
// MFMA clusters (T5: attn waves at different phases).
__global__ __launch_bounds__(128, 2) void attn10_kernel(
    const bf16_t* __restrict__ Q, const bf16_t* __restrict__ Kp,
    const bf16_t* __restrict__ Vp, const float2* __restrict__ cf,
    bf16_t* __restrict__ out)
{
  __shared__ float buf[128 * 33];
  __shared__ float mlS[2][32];

  const int t = threadIdx.x;
  const int w = t >> 6;
  const int l = t & 63;
  const int q5 = l & 31;
  const int hi = l >> 5;
  const int h = blockIdx.x & 7;
  const int q0 = (blockIdx.x >> 3) * 32;
  const float LOG2E = 1.44269504088896f;
  const float isq = 0.08838834764831845f;
  const float itau = 1.6666666666666667f;
  const float hs = 1.0f / (float)(2 << h);
  const float ap = isq * LOG2E;
  const float an = -isq * itau * LOG2E;
  const float bpp = hs * LOG2E;

  bf16x8 qf[8];
  {
    const bf16_t* qrow = Q + (size_t)(q0 + q5) * DMODEL + h * DHEAD;
#pragma unroll
    for (int c = 0; c < 8; c++)
      qf[c] = *reinterpret_cast<const bf16x8*>(qrow + c * 16 + hi * 8);
  }
  const float2 qc = cf[q0 + q5];
  const float qxs = qc.x * bpp, qys = qc.y * bpp;

  f32x16 accp[4], accn[4];
#pragma unroll
  for (int f = 0; f < 4; f++) {
#pragma unroll
    for (int r = 0; r < 16; r++) { accp[f][r] = 0.f; accn[f][r] = 0.f; }
  }
  float lp = 0.f, lN = 0.f;

  const bf16_t* kpb = Kp + ((size_t)(h * 128 + w * 64)) * 4096 + l * 8;
  const bf16_t* vpb = Vp + ((size_t)(h * 128 + w * 64)) * 4096 + l * 8;

  for (int it = 0; it < 64; it++) {
    const int kv0 = w * 2048 + it * 32;

    bf16x8 kf[8];
#pragma unroll
    for (int c = 0; c < 8; c++)
      kf[c] = *reinterpret_cast<const bf16x8*>(kpb + (size_t)it * 4096 + c * 512);

    f32x16 sacc, sacc2;
#pragma unroll
    for (int r = 0; r < 16; r++) { sacc[r] = 0.f; sacc2[r] = 0.f; }
    __builtin_amdgcn_s_setprio(1);
#pragma unroll
    for (int c = 0; c < 4; c++) {
      sacc = __builtin_amdgcn_mfma_f32_32x32x16_bf16(kf[2 * c], qf[2 * c], sacc, 0, 0, 0);
      sacc2 = __builtin_amdgcn_mfma_f32_32x32x16_bf16(kf[2 * c + 1], qf[2 * c + 1], sacc2, 0, 0, 0);
    }
    __builtin_amdgcn_s_setprio(0);

    bf16x8 vf[8];
#pragma unroll
    for (int fr = 0; fr < 8; fr++)
      vf[fr] = *reinterpret_cast<const bf16x8*>(vpb + (size_t)it * 4096 + fr * 512);

#pragma unroll
    for (int r = 0; r < 16; r++) sacc[r] += sacc2[r];

    float p16[16], n16[16];
#pragma unroll
    for (int r = 0; r < 16; r++) {
      int kvr = kv0 + (r & 3) + 8 * (r >> 2) + 4 * hi;
      float2 c = cf[kvr];
      float dx = __builtin_fmaf(c.x, -bpp, qxs);
      float dy = __builtin_fmaf(c.y, -bpp, qys);
      float u = fsqrt(__builtin_fmaf(dy, dy, dx * dx));
      float pv = fexp2(__builtin_fmaf(sacc[r], ap, -u));
      float nv = fexp2(__builtin_fmaf(sacc[r], an, u * -itau));
      p16[r] = pv; n16[r] = nv;
      lp += pv; lN += nv;
    }

    // pack P^T -> bf16 B-frags via v_permlane32_swap_b32:
    // newA = {A.lo32, B.lo32}, newB = {A.hi32, B.hi32}
    // pw[u] low = own A, high = B from lane-32; pw[2+u] low = A from lane+32, high = own B.
    unsigned pw[2][4], nw[2][4];
#pragma unroll
    for (int ks = 0; ks < 2; ks++) {
#pragma unroll
      for (int u = 0; u < 2; u++) {
        unsigned A = cvtpk(p16[8 * ks + 2 * u], p16[8 * ks + 2 * u + 1]);
        unsigned B = cvtpk(p16[8 * ks + 4 + 2 * u], p16[8 * ks + 4 + 2 * u + 1]);
        asm("v_permlane32_swap_b32 %0, %1" : "+v"(A), "+v"(B));
        pw[ks][u] = A;
        pw[ks][2 + u] = B;
        unsigned C = cvtpk(n16[8 * ks + 2 * u], n16[8 * ks + 2 * u + 1]);
        unsigned D = cvtpk(n16[8 * ks + 4 + 2 * u], n16[8 * ks + 4 + 2 * u + 1]);
        asm("v_permlane32_swap_b32 %0, %1" : "+v"(C), "+v"(D));
        nw[ks][u] = C;
        nw[ks][2 + u] = D;
      }
    }

    __builtin_amdgcn_s_setprio(1);
#pragma unroll
    for (int ks = 0; ks < 2; ks++) {
      union { unsigned u[4]; bf16x8 v; } pb, nb;
#pragma unroll
      for (int j = 0; j < 4; j++) { pb.u[j] = pw[ks][j]; nb.u[j] = nw[ks][j]; }
#pragma unroll
      for (int f = 0; f < 4; f++) {
        accp[f] = __builtin_amdgcn_mfma_f32_32x32x16_bf16(vf[ks * 4 + f], pb.v, accp[f], 0, 0, 0);
        accn[f] = __builtin_amdgcn_mfma_f32_32x32x16_bf16(vf[ks * 4 + f], nb.v, accn[f], 0, 0, 0);
      }
    }
    __builtin_amdgcn_s_setprio(0);
  }

  float lpw = lp + __shfl_xor(lp, 32, 64);
  float lnw = lN + __shfl_xor(lN, 32, 64);

  __syncthreads();
  if (w == 1) {
    if (hi == 0) { mlS[0][q5] = lpw; mlS[1][q5] = lnw; }
#pragma unroll
    for (int f = 0; f < 4; f++)
#pragma unroll
      for (int r = 0; r < 16; r++)
        buf[(32 * f + (r & 3) + 8 * (r >> 2) + 4 * hi) * 33 + q5] = accp[f][r];
  }
  __syncthreads();
  float lpt = 0.f, lnt = 0.f;
  if (w == 0) {
    lpt = lpw + mlS[0][q5];
    lnt = lnw + mlS[1][q5];
#pragma unroll
    for (int f = 0; f < 4; f++)
#pragma unroll
      for (int r = 0; r < 16; r++)
        accp[f][r] += buf[(32 * f + (r & 3) + 8 * (r >> 2) + 4 * hi) * 33 + q5];
  }
  __syncthreads();
  if (w == 1) {
#pragma unroll
    for (int f = 0; f < 4; f++)
#pragma unroll
      for (int r = 0; r < 16; r++)
        buf[(32 * f + (r & 3) + 8 * (r >> 2) + 4 * hi) * 33 + q5] = accn[f][r];
  }
  __syncthreads();
  if (w == 0) {
    float ip = 1.f / lpt, inn = 1.5f / lnt;
#pragma unroll
    for (int f = 0; f < 4; f++)
#pragma unroll
      for (int r = 0; r < 16; r++) {
        int row = 32 * f + (r & 3) + 8 * (r >> 2) + 4 * hi;
        float an2 = accn[f][r] + buf[row * 33 + q5];
        buf[row * 33 + q5] = accp[f][r] * ip - an2 * inn;
      }
  }
  __syncthreads();

  {
    int q = t >> 2, dq = (t & 3) * 32;
#pragma unroll
    for (int j = 0; j < 4; j++) {
      bf16x8 ov;
#pragma unroll
      for (int e = 0; e < 8; e++) ov[e] = (bf16_t)buf[(dq + j * 8 + e) * 33 + q];
      *reinterpret_cast<bf16x8*>(out + (size_t)(q0 + q) * DMODEL + h * DHEAD + dq + j * 8) = ov;
    }
  }
}

// ---------------- row LayerNorm (D=1024) ----------------
__global__ __launch_bounds__(256) void ln_kernel(
    const float* __restrict__ in, const float* __restrict__ g, const float* __restrict__ b,
    float* __restrict__ outF, bf16_t* __restrict__ outH)
{
  int row = blockIdx.x, t = threadIdx.x;
  const float4 v = reinterpret_cast<const float4*>(in + (size_t)row * DMODEL)[t];
  float s = v.x + v.y + v.z + v.w;
  float ss = v.x * v.x + v.y * v.y + v.z * v.z + v.w * v.w;
#pragma unroll
  for (int m = 32; m >= 1; m >>= 1) {
    s += __shfl_xor(s, m, 64);
    ss += __shfl_xor(ss, m, 64);
  }
  __shared__ float red[8];
  int w = t >> 6, l = t & 63;
  if (l == 0) { red[w] = s; red[4 + w] = ss; }
  __syncthreads();
  s = red[0] + red[1] + red[2] + red[3];
  ss = red[4] + red[5] + red[6] + red[7];
  float mu = s * (1.f / DMODEL);
  float var = ss * (1.f / DMODEL) - mu * mu;
  float rs = rsqrtf(var + LNEPS);
  const float4 gv = reinterpret_cast<const float4*>(g)[t];
  const float4 bv = reinterpret_cast<const float4*>(b)[t];
  float y0 = (v.x - mu) * rs * gv.x + bv.x;
  float y1 = (v.y - mu) * rs * gv.y + bv.y;
  float y2 = (v.z - mu) * rs * gv.z + bv.z;
  float y3 = (v.w - mu) * rs * gv.w + bv.w;
  if (outF) {
    float4 o; o.x = y0; o.y = y1; o.z = y2; o.w = y3;
    reinterpret_cast<float4*>(outF + (size_t)row * DMODEL)[t] = o;
  }
  if (outH) {
    bf16x4 o = {(bf16_t)y0, (bf16_t)y1, (bf16_t)y2, (bf16_t)y3};
    reinterpret_cast<bf16x4*>(outH + (size_t)row * DMODEL)[t] = o;
  }
}

extern "C" void kernel_launch(void* const* d_in, const int* in_sizes, int n_in,
                              void* d_out, int out_size, void* d_ws, size_t ws_size,
                              hipStream_t stream) {
  (void)in_sizes; (void)n_in; (void)out_size; (void)ws_size;
  const float* features = (const float*)d_in[0];
  const int* coords = (const int*)d_in[1];
  const float* Wq = (const float*)d_in[2];
  const float* Wk = (const float*)d_in[3];
  const float* Wv = (const float*)d_in[4];
  const float* Wo = (const float*)d_in[5];
  const float* bo = (const float*)d_in[6];
  const float* ln1g = (const float*)d_in[7];
  const float* ln1b = (const float*)d_in[8];
  const float* W1 = (const float*)d_in[9];
  const float* b1 = (const float*)d_in[10];
  const float* W2 = (const float*)d_in[11];
  const float* b2 = (const float*)d_in[12];
  const float* ln2g = (const float*)d_in[13];
  const float* ln2b = (const float*)d_in[14];
  float* outp = (float*)d_out;

  char* ws = (char*)d_ws;
  size_t off = 0;
  auto alloc = [&](size_t bytes) -> void* {
    void* p = ws + off;
    off += (bytes + 255) & ~((size_t)255);
    return p;
  };
  bf16_t* fb16 = (bf16_t*)alloc((size_t)NTOK * DMODEL * 2);
  bf16_t* wqkv16 = (bf16_t*)alloc((size_t)3 * DMODEL * DMODEL * 2);
  bf16_t* wo16 = (bf16_t*)alloc((size_t)DMODEL * DMODEL * 2);
  bf16_t* w116 = (bf16_t*)alloc((size_t)DFFN * DMODEL * 2);
  bf16_t* w216 = (bf16_t*)alloc((size_t)DMODEL * DFFN * 2);
  bf16_t* q16 = (bf16_t*)alloc((size_t)NTOK * DMODEL * 2);
  bf16_t* Kp = (bf16_t*)alloc((size_t)NTOK * DMODEL * 2);
  bf16_t* Vp = (bf16_t*)alloc((size_t)NTOK * DMODEL * 2);
  float* acc1 = (float*)alloc((size_t)NTOK * DMODEL * 4);
  bf16_t* x16 = (bf16_t*)alloc((size_t)NTOK * DMODEL * 2);
  bf16_t* h16 = (bf16_t*)alloc((size_t)NTOK * DFFN * 2);
  float2* cfl = (float2*)alloc((size_t)NTOK * sizeof(float2));
  bf16_t* att16 = fb16;

  cvt_all<<<dim3(2048), 256, 0, stream>>>(features, Wq, Wk, Wv, Wo, W1, W2, coords,
                                          fb16, wqkv16, wo16, w116, w216, cfl);

  gemm_qkv<<<dim3(NTOK / 128, 3 * DMODEL / 128), 256, 0, stream>>>(fb16, wqkv16, q16, Kp, Vp);
  attn10_kernel<<<dim3(NTOK / 32 * NHEAD), 128, 0, stream>>>(q16, Kp, Vp, cfl, att16);
  dim3 gO(NTOK / 64, DMODEL / 128);
  gemm_bt<1><<<gO, 256, 0, stream>>>(att16, wo16, NTOK, DMODEL, DMODEL, bo, features, nullptr, acc1, nullptr);
  ln_kernel<<<dim3(NTOK), 256, 0, stream>>>(acc1, ln1g, ln1b, nullptr, x16);
  gemm_bt<2><<<dim3(NTOK / 64, DFFN / 128), 256, 0, stream>>>(x16, w116, NTOK, DFFN, DMODEL, b1, nullptr, nullptr, nullptr, h16);
  gemm_bt<3><<<gO, 256, 0, stream>>>(h16, w216, NTOK, DMODEL, DFFN, b2, nullptr, x16, acc1, nullptr);
  ln_kernel<<<dim3(NTOK), 256, 0, stream>>>(acc1, ln2g, ln2b, outp, nullptr);
}

// Round 15
// 299.640 us; speedup vs baseline: 1.0500x; 1.0500x over previous
//
#include <hip/hip_runtime.h>
#include <cstdint>
#include <cstddef>

#define NTOK 4096
#define DMODEL 1024
#define NHEAD 8
#define DHEAD 128
#define DFFN 1536
#define LNEPS 1e-5f

typedef __bf16 bf16_t;
typedef __bf16 bf16x8 __attribute__((ext_vector_type(8)));
typedef __bf16 bf16x4 __attribute__((ext_vector_type(4)));
typedef float f32x4 __attribute__((ext_vector_type(4)));
typedef float f32x16 __attribute__((ext_vector_type(16)));

__device__ __forceinline__ void gload_lds16(const bf16_t* g, bf16_t* lds) {
  __builtin_amdgcn_global_load_lds(
      (const __attribute__((address_space(1))) unsigned int*)g,
      (__attribute__((address_space(3))) unsigned int*)lds, 16, 0, 0);
}

// raw-ISA math (single instruction each; ~1ulp, fine for bf16 outputs)
__device__ __forceinline__ float fexp2(float x) {
  float r;
  asm("v_exp_f32 %0, %1" : "=v"(r) : "v"(x));
  return r;
}
__device__ __forceinline__ float fsqrt(float x) {
  float r;
  asm("v_sqrt_f32 %0, %1" : "=v"(r) : "v"(x));
  return r;
}
__device__ __forceinline__ unsigned cvtpk(float lo, float hi) {
  unsigned r;
  asm("v_cvt_pk_bf16_f32 %0, %1, %2" : "=v"(r) : "v"(lo), "v"(hi));
  return r;
}

// ---------------- mega convert: all weights + features + coords, 1 launch ----------------
#define CVT_TOTAL 2885632
__global__ __launch_bounds__(256) void cvt_all(
    const float* __restrict__ f, const float* __restrict__ wq,
    const float* __restrict__ wk, const float* __restrict__ wv,
    const float* __restrict__ wo, const float* __restrict__ w1,
    const float* __restrict__ w2, const int* __restrict__ coords,
    bf16_t* __restrict__ fb, bf16_t* __restrict__ wqkv,
    bf16_t* __restrict__ wob, bf16_t* __restrict__ w1b,
    bf16_t* __restrict__ w2b, float2* __restrict__ cfl)
{
  for (int u = blockIdx.x * 256 + threadIdx.x; u < CVT_TOTAL; u += 2048 * 256) {
    if (u < 2048) {
      int4 c = reinterpret_cast<const int4*>(coords)[u];
      float4 o;
      o.x = (float)c.x; o.y = (float)c.y; o.z = (float)c.z; o.w = (float)c.w;
      reinterpret_cast<float4*>(cfl)[u] = o;
      continue;
    }
    int v = u - 2048;
    const float* src; bf16_t* dst; int base;
    if (v < 1048576)      { src = f;  dst = fb;            base = 0; }
    else if (v < 1310720) { src = wq; dst = wqkv;          base = 1048576; }
    else if (v < 1572864) { src = wk; dst = wqkv + 1048576; base = 1310720; }
    else if (v < 1835008) { src = wv; dst = wqkv + 2097152; base = 1572864; }
    else if (v < 2097152) { src = wo; dst = wob;           base = 1835008; }
    else if (v < 2490368) { src = w1; dst = w1b;           base = 2097152; }
    else                  { src = w2; dst = w2b;           base = 2490368; }
    int local = v - base;
    const float4 x = reinterpret_cast<const float4*>(src)[local];
    bf16x4 o = {(bf16_t)x.x, (bf16_t)x.y, (bf16_t)x.z, (bf16_t)x.w};
    reinterpret_cast<bf16x4*>(dst)[local] = o;
  }
}

// ---------------- bf16 GEMM, C = A @ B^T, 64x128 tile, LDS dbuf ----------------
template<int EPI>
__global__ __launch_bounds__(256) void gemm_bt(
    const bf16_t* __restrict__ A, const bf16_t* __restrict__ B,
    int M, int Nn, int K,
    const float* __restrict__ bias, const float* __restrict__ resid,
    const bf16_t* __restrict__ residH,
    float* __restrict__ outF, bf16_t* __restrict__ outH)
{
  __shared__ bf16_t As[2][64 * 32];
  __shared__ bf16_t Bs[2][128 * 32];
  const int t = threadIdx.x;
  const int w = t >> 6, l = t & 63;
  const int lg = l >> 4, li = l & 15;
  const int m0 = blockIdx.x * 64, n0 = blockIdx.y * 128;
  const int wr = (w >> 1) * 32, wc = (w & 1) * 64;
  const f32x4 fz = {0.f, 0.f, 0.f, 0.f};
  f32x4 acc[2][4];
#pragma unroll
  for (int i = 0; i < 2; i++)
#pragma unroll
    for (int j = 0; j < 4; j++) acc[i][j] = fz;

  const bf16_t* Ag = A + (size_t)m0 * K;
  const bf16_t* Bg = B + (size_t)n0 * K;
  const int ca = w * 64 + l;
  const int nK = K >> 5;

  gload_lds16(Ag + (size_t)(ca >> 2) * K + (ca & 3) * 8, &As[0][(w * 64) * 8]);
#pragma unroll
  for (int p = 0; p < 2; p++) {
    int cb = p * 256 + ca;
    gload_lds16(Bg + (size_t)(cb >> 2) * K + (cb & 3) * 8, &Bs[0][(p * 256 + w * 64) * 8]);
  }
  __syncthreads();

  for (int ki = 0; ki < nK; ki++) {
    const int cur = ki & 1;
    if (ki + 1 < nK) {
      const int kt = (ki + 1) << 5;
      gload_lds16(Ag + (size_t)(ca >> 2) * K + kt + (ca & 3) * 8,
                  &As[cur ^ 1][(w * 64) * 8]);
#pragma unroll
      for (int p = 0; p < 2; p++) {
        int cb = p * 256 + ca;
        gload_lds16(Bg + (size_t)(cb >> 2) * K + kt + (cb & 3) * 8,
                    &Bs[cur ^ 1][(p * 256 + w * 64) * 8]);
      }
    }
    bf16x8 af[2], bfr[4];
#pragma unroll
    for (int mi = 0; mi < 2; mi++)
      af[mi] = *reinterpret_cast<const bf16x8*>(&As[cur][(wr + mi * 16 + li) * 32 + lg * 8]);
#pragma unroll
    for (int ni = 0; ni < 4; ni++)
      bfr[ni] = *reinterpret_cast<const bf16x8*>(&Bs[cur][(wc + ni * 16 + li) * 32 + lg * 8]);
#pragma unroll
    for (int mi = 0; mi < 2; mi++)
#pragma unroll
      for (int ni = 0; ni < 4; ni++)
        acc[mi][ni] = __builtin_amdgcn_mfma_f32_16x16x32_bf16(af[mi], bfr[ni], acc[mi][ni], 0, 0, 0);
    __syncthreads();
  }

#pragma unroll
  for (int mi = 0; mi < 2; mi++) {
#pragma unroll
    for (int ni = 0; ni < 4; ni++) {
      int gcol = n0 + wc + ni * 16 + li;
#pragma unroll
      for (int r = 0; r < 4; r++) {
        int grow = m0 + wr + mi * 16 + lg * 4 + r;
        float v = acc[mi][ni][r];
        if (EPI == 0) {
          outH[(size_t)grow * Nn + gcol] = (bf16_t)v;
        } else if (EPI == 1) {
          v += bias[gcol] + resid[(size_t)grow * Nn + gcol];
          outF[(size_t)grow * Nn + gcol] = v;
        } else if (EPI == 2) {
          v += bias[gcol];
          v = 0.5f * v * (1.f + erff(v * 0.70710678118654752f));
          outH[(size_t)grow * Nn + gcol] = (bf16_t)v;
        } else {
          v += bias[gcol] + (float)residH[(size_t)grow * Nn + gcol];
          outF[(size_t)grow * Nn + gcol] = v;
        }
      }
    }
  }
}

// ---------------- fused QKV GEMM: 128x128 tile (m97-class), dbuf, scatter epi ----------------
__global__ __launch_bounds__(256) void gemm_qkv(
    const bf16_t* __restrict__ A, const bf16_t* __restrict__ B,
    bf16_t* __restrict__ Qo, bf16_t* __restrict__ Kp, bf16_t* __restrict__ Vp)
{
  const int K = DMODEL;
  __shared__ bf16_t As[2][128 * 32];
  __shared__ bf16_t Bs[2][128 * 32];
  const int t = threadIdx.x;
  const int w = t >> 6, l = t & 63;
  const int lg = l >> 4, li = l & 15;
  const int m0 = blockIdx.x * 128, n0 = blockIdx.y * 128;
  const int wr = (w >> 1) * 64, wc = (w & 1) * 64;
  const f32x4 fz = {0.f, 0.f, 0.f, 0.f};
  f32x4 acc[4][4];
#pragma unroll
  for (int i = 0; i < 4; i++)
#pragma unroll
    for (int j = 0; j < 4; j++) acc[i][j] = fz;

  const bf16_t* Ag = A + (size_t)m0 * K;
  const bf16_t* Bg = B + (size_t)n0 * K;
  const int nK = K >> 5;

#pragma unroll
  for (int p = 0; p < 2; p++) {
    int c = p * 256 + w * 64 + l;
    gload_lds16(Ag + (size_t)(c >> 2) * K + (c & 3) * 8, &As[0][(p * 256 + w * 64) * 8]);
    gload_lds16(Bg + (size_t)(c >> 2) * K + (c & 3) * 8, &Bs[0][(p * 256 + w * 64) * 8]);
  }
  __syncthreads();

  for (int ki = 0; ki < nK; ki++) {
    const int cur = ki & 1;
    if (ki + 1 < nK) {
      const int kt = (ki + 1) << 5;
#pragma unroll
      for (int p = 0; p < 2; p++) {
        int c = p * 256 + w * 64 + l;
        gload_lds16(Ag + (size_t)(c >> 2) * K + kt + (c & 3) * 8,
                    &As[cur ^ 1][(p * 256 + w * 64) * 8]);
        gload_lds16(Bg + (size_t)(c >> 2) * K + kt + (c & 3) * 8,
                    &Bs[cur ^ 1][(p * 256 + w * 64) * 8]);
      }
    }
    bf16x8 af[4], bfr[4];
#pragma unroll
    for (int mi = 0; mi < 4; mi++)
      af[mi] = *reinterpret_cast<const bf16x8*>(&As[cur][(wr + mi * 16 + li) * 32 + lg * 8]);
#pragma unroll
    for (int ni = 0; ni < 4; ni++)
      bfr[ni] = *reinterpret_cast<const bf16x8*>(&Bs[cur][(wc + ni * 16 + li) * 32 + lg * 8]);
#pragma unroll
    for (int mi = 0; mi < 4; mi++)
#pragma unroll
      for (int ni = 0; ni < 4; ni++)
        acc[mi][ni] = __builtin_amdgcn_mfma_f32_16x16x32_bf16(af[mi], bfr[ni], acc[mi][ni], 0, 0, 0);
    __syncthreads();
  }

  const int region = n0 >> 10;   // block-uniform: 0=Q, 1=K, 2=V
#pragma unroll
  for (int mi = 0; mi < 4; mi++) {
#pragma unroll
    for (int ni = 0; ni < 4; ni++) {
      int gcol = n0 + wc + ni * 16 + li;
#pragma unroll
      for (int r = 0; r < 4; r++) {
        int token = m0 + wr + mi * 16 + lg * 4 + r;
        bf16_t v = (bf16_t)acc[mi][ni][r];
        if (region == 0) {
          Qo[(size_t)token * DMODEL + gcol] = v;
        } else if (region == 1) {
          int gc = gcol - 1024;
          int h = gc >> 7, d = gc & 127;
          size_t addr = ((size_t)(h * 128 + (token >> 5))) * 4096 +
                        (d >> 4) * 512 + ((d >> 3) & 1) * 256 + (token & 31) * 8 + (d & 7);
          Kp[addr] = v;
        } else {
          int gc = gcol - 2048;
          int h = gc >> 7, dh = gc & 127;
          size_t addr = ((size_t)(h * 128 + (token >> 5))) * 4096 +
                        (((token >> 4) & 1) * 4 + (dh >> 5)) * 512 +
                        ((token >> 3) & 1) * 256 + (dh & 31) * 8 + (token & 7);
          Vp[addr] = v;
        }
      }
    }
  }
}

// ---------------- fused dual-softmax flash attention, v9 (verified 173us) ----------------
__global__ __launch_bounds__(128, 2) void attn9_kernel(
    const bf16_t* __restrict__ Q, const bf16_t* __restrict__ Kp,
    const bf16_t* __restrict__ Vp, const float2* __restrict__ cf,
    bf16_t* __restrict__ out)
{
  __shared__ float buf[128 * 33];
  __shared__ float mlS[2][32];

  const int t = threadIdx.x;
  const int w = t >> 6;
  const int l = t & 63;
  const int q5 = l & 31;
  const int hi = l >> 5;
  const int h = blockIdx.x & 7;
  const int q0 = (blockIdx.x >> 3) * 32;
  const float LOG2E = 1.44269504088896f;
  const float isq = 0.08838834764831845f;
  const float itau = 1.6666666666666667f;
  const float hs = 1.0f / (float)(2 << h);
  const float ap = isq * LOG2E;
  const float an = -isq * itau * LOG2E;
  const float bpp = hs * LOG2E;

  bf16x8 qf[8];
  {
    const bf16_t* qrow = Q + (size_t)(q0 + q5) * DMODEL + h * DHEAD;
#pragma unroll
    for (int c = 0; c < 8; c++)
      qf[c] = *reinterpret_cast<const bf16x8*>(qrow + c * 16 + hi * 8);
  }
  const float2 qc = cf[q0 + q5];
  const float qxs = qc.x * bpp, qys = qc.y * bpp;

  f32x16 accp[4], accn[4];
#pragma unroll
  for (int f = 0; f < 4; f++) {
#pragma unroll
    for (int r = 0; r < 16; r++) { accp[f][r] = 0.f; accn[f][r] = 0.f; }
  }
  float lp = 0.f, lN = 0.f;

  const bf16_t* kpb = Kp + ((size_t)(h * 128 + w * 64)) * 4096 + l * 8;
  const bf16_t* vpb = Vp + ((size_t)(h * 128 + w * 64)) * 4096 + l * 8;

  for (int it = 0; it < 64; it++) {
    const int kv0 = w * 2048 + it * 32;

    bf16x8 kf[8];
#pragma unroll
    for (int c = 0; c < 8; c++)
      kf[c] = *reinterpret_cast<const bf16x8*>(kpb + (size_t)it * 4096 + c * 512);

    f32x16 sacc, sacc2;
#pragma unroll
    for (int r = 0; r < 16; r++) { sacc[r] = 0.f; sacc2[r] = 0.f; }
#pragma unroll
    for (int c = 0; c < 4; c++) {
      sacc = __builtin_amdgcn_mfma_f32_32x32x16_bf16(kf[2 * c], qf[2 * c], sacc, 0, 0, 0);
      sacc2 = __builtin_amdgcn_mfma_f32_32x32x16_bf16(kf[2 * c + 1], qf[2 * c + 1], sacc2, 0, 0, 0);
    }

    bf16x8 vf[8];
#pragma unroll
    for (int fr = 0; fr < 8; fr++)
      vf[fr] = *reinterpret_cast<const bf16x8*>(vpb + (size_t)it * 4096 + fr * 512);

#pragma unroll
    for (int r = 0; r < 16; r++) sacc[r] += sacc2[r];

    float p16[16], n16[16];
#pragma unroll
    for (int r = 0; r < 16; r++) {
      int kvr = kv0 + (r & 3) + 8 * (r >> 2) + 4 * hi;
      float2 c = cf[kvr];
      float dx = __builtin_fmaf(c.x, -bpp, qxs);
      float dy = __builtin_fmaf(c.y, -bpp, qys);
      float u = fsqrt(__builtin_fmaf(dy, dy, dx * dx));
      float pv = fexp2(__builtin_fmaf(sacc[r], ap, -u));
      float nv = fexp2(__builtin_fmaf(sacc[r], an, u * -itau));
      p16[r] = pv; n16[r] = nv;
      lp += pv; lN += nv;
    }

    unsigned pw[2][4], nw[2][4];
#pragma unroll
    for (int ks = 0; ks < 2; ks++) {
#pragma unroll
      for (int u = 0; u < 2; u++) {
        unsigned A = cvtpk(p16[8 * ks + 2 * u], p16[8 * ks + 2 * u + 1]);
        unsigned B = cvtpk(p16[8 * ks + 4 + 2 * u], p16[8 * ks + 4 + 2 * u + 1]);
        unsigned Ax = __shfl_xor(A, 32, 64);
        unsigned Bx = __shfl_xor(B, 32, 64);
        pw[ks][u] = hi ? Bx : A;
        pw[ks][2 + u] = hi ? B : Ax;
        unsigned C = cvtpk(n16[8 * ks + 2 * u], n16[8 * ks + 2 * u + 1]);
        unsigned D = cvtpk(n16[8 * ks + 4 + 2 * u], n16[8 * ks + 4 + 2 * u + 1]);
        unsigned Cx = __shfl_xor(C, 32, 64);
        unsigned Dx = __shfl_xor(D, 32, 64);
        nw[ks][u] = hi ? Dx : C;
        nw[ks][2 + u] = hi ? D : Cx;
      }
    }

#pragma unroll
    for (int ks = 0; ks < 2; ks++) {
      union { unsigned u[4]; bf16x8 v; } pb, nb;
#pragma unroll
      for (int j = 0; j < 4; j++) { pb.u[j] = pw[ks][j]; nb.u[j] = nw[ks][j]; }
#pragma unroll
      for (int f = 0; f < 4; f++) {
        accp[f] = __builtin_amdgcn_mfma_f32_32x32x16_bf16(vf[ks * 4 + f], pb.v, accp[f], 0, 0, 0);
        accn[f] = __builtin_amdgcn_mfma_f32_32x32x16_bf16(vf[ks * 4 + f], nb.v, accn[f], 0, 0, 0);
      }
    }
  }

  float lpw = lp + __shfl_xor(lp, 32, 64);
  float lnw = lN + __shfl_xor(lN, 32, 64);

  __syncthreads();
  if (w == 1) {
    if (hi == 0) { mlS[0][q5] = lpw; mlS[1][q5] = lnw; }
#pragma unroll
    for (int f = 0; f < 4; f++)
#pragma unroll
      for (int r = 0; r < 16; r++)
        buf[(32 * f + (r & 3) + 8 * (r >> 2) + 4 * hi) * 33 + q5] = accp[f][r];
  }
  __syncthreads();
  float lpt = 0.f, lnt = 0.f;
  if (w == 0) {
    lpt = lpw + mlS[0][q5];
    lnt = lnw + mlS[1][q5];
#pragma unroll
    for (int f = 0; f < 4; f++)
#pragma unroll
      for (int r = 0; r < 16; r++)
        accp[f][r] += buf[(32 * f + (r & 3) + 8 * (r >> 2) + 4 * hi) * 33 + q5];
  }
  __syncthreads();
  if (w == 1) {
#pragma unroll
    for (int f = 0; f < 4; f++)
#pragma unroll
      for (int r = 0; r < 16; r++)
        buf[(32 * f + (r & 3) + 8 * (r >> 2) + 4 * hi) * 33 + q5] = accn[f][r];
  }
  __syncthreads();
  if (w == 0) {
    float ip = 1.f / lpt, inn = 1.5f / lnt;
#pragma unroll
    for (int f = 0; f < 4; f++)
#pragma unroll
      for (int r = 0; r < 16; r++) {
        int row = 32 * f + (r & 3) + 8 * (r >> 2) + 4 * hi;
        float an2 = accn[f][r] + buf[row * 33 + q5];
        buf[row * 33 + q5] = accp[f][r] * ip - an2 * inn;
      }
  }
  __syncthreads();

  {
    int q = t >> 2, dq = (t & 3) * 32;
#pragma unroll
    for (int j = 0; j < 4; j++) {
      bf16x8 ov;
#pragma unroll
      for (int e = 0; e < 8; e++) ov[e] = (bf16_t)buf[(dq + j * 8 + e) * 33 + q];
      *reinterpret_cast<bf16x8*>(out + (size_t)(q0 + q) * DMODEL + h * DHEAD + dq + j * 8) = ov;
    }
  }
}

// ---------------- row LayerNorm (D=1024) ----------------
__global__ __launch_bounds__(256) void ln_kernel(
    const float* __restrict__ in, const float* __restrict__ g, const float* __restrict__ b,
    float* __restrict__ outF, bf16_t* __restrict__ outH)
{
  int row = blockIdx.x, t = threadIdx.x;
  const float4 v = reinterpret_cast<const float4*>(in + (size_t)row * DMODEL)[t];
  float s = v.x + v.y + v.z + v.w;
  float ss = v.x * v.x + v.y * v.y + v.z * v.z + v.w * v.w;
#pragma unroll
  for (int m = 32; m >= 1; m >>= 1) {
    s += __shfl_xor(s, m, 64);
    ss += __shfl_xor(ss, m, 64);
  }
  __shared__ float red[8];
  int w = t >> 6, l = t & 63;
  if (l == 0) { red[w] = s; red[4 + w] = ss; }
  __syncthreads();
  s = red[0] + red[1] + red[2] + red[3];
  ss = red[4] + red[5] + red[6] + red[7];
  float mu = s * (1.f / DMODEL);
  float var = ss * (1.f / DMODEL) - mu * mu;
  float rs = rsqrtf(var + LNEPS);
  const float4 gv = reinterpret_cast<const float4*>(g)[t];
  const float4 bv = reinterpret_cast<const float4*>(b)[t];
  float y0 = (v.x - mu) * rs * gv.x + bv.x;
  float y1 = (v.y - mu) * rs * gv.y + bv.y;
  float y2 = (v.z - mu) * rs * gv.z + bv.z;
  float y3 = (v.w - mu) * rs * gv.w + bv.w;
  if (outF) {
    float4 o; o.x = y0; o.y = y1; o.z = y2; o.w = y3;
    reinterpret_cast<float4*>(outF + (size_t)row * DMODEL)[t] = o;
  }
  if (outH) {
    bf16x4 o = {(bf16_t)y0, (bf16_t)y1, (bf16_t)y2, (bf16_t)y3};
    reinterpret_cast<bf16x4*>(outH + (size_t)row * DMODEL)[t] = o;
  }
}

extern "C" void kernel_launch(void* const* d_in, const int* in_sizes, int n_in,
                              void* d_out, int out_size, void* d_ws, size_t ws_size,
                              hipStream_t stream) {
  (void)in_sizes; (void)n_in; (void)out_size; (void)ws_size;
  const float* features = (const float*)d_in[0];
  const int* coords = (const int*)d_in[1];
  const float* Wq = (const float*)d_in[2];
  const float* Wk = (const float*)d_in[3];
  const float* Wv = (const float*)d_in[4];
  const float* Wo = (const float*)d_in[5];
  const float* bo = (const float*)d_in[6];
  const float* ln1g = (const float*)d_in[7];
  const float* ln1b = (const float*)d_in[8];
  const float* W1 = (const float*)d_in[9];
  const float* b1 = (const float*)d_in[10];
  const float* W2 = (const float*)d_in[11];
  const float* b2 = (const float*)d_in[12];
  const float* ln2g = (const float*)d_in[13];
  const float* ln2b = (const float*)d_in[14];
  float* outp = (float*)d_out;

  char* ws = (char*)d_ws;
  size_t off = 0;
  auto alloc = [&](size_t bytes) -> void* {
    void* p = ws + off;
    off += (bytes + 255) & ~((size_t)255);
    return p;
  };
  bf16_t* fb16 = (bf16_t*)alloc((size_t)NTOK * DMODEL * 2);
  bf16_t* wqkv16 = (bf16_t*)alloc((size_t)3 * DMODEL * DMODEL * 2);
  bf16_t* wo16 = (bf16_t*)alloc((size_t)DMODEL * DMODEL * 2);
  bf16_t* w116 = (bf16_t*)alloc((size_t)DFFN * DMODEL * 2);
  bf16_t* w216 = (bf16_t*)alloc((size_t)DMODEL * DFFN * 2);
  bf16_t* q16 = (bf16_t*)alloc((size_t)NTOK * DMODEL * 2);
  bf16_t* Kp = (bf16_t*)alloc((size_t)NTOK * DMODEL * 2);
  bf16_t* Vp = (bf16_t*)alloc((size_t)NTOK * DMODEL * 2);
  float* acc1 = (float*)alloc((size_t)NTOK * DMODEL * 4);
  bf16_t* x16 = (bf16_t*)alloc((size_t)NTOK * DMODEL * 2);
  bf16_t* h16 = (bf16_t*)alloc((size_t)NTOK * DFFN * 2);
  float2* cfl = (float2*)alloc((size_t)NTOK * sizeof(float2));
  bf16_t* att16 = fb16;

  cvt_all<<<dim3(2048), 256, 0, stream>>>(features, Wq, Wk, Wv, Wo, W1, W2, coords,
                                          fb16, wqkv16, wo16, w116, w216, cfl);

  gemm_qkv<<<dim3(NTOK / 128, 3 * DMODEL / 128), 256, 0, stream>>>(fb16, wqkv16, q16, Kp, Vp);
  attn9_kernel<<<dim3(NTOK / 32 * NHEAD), 128, 0, stream>>>(q16, Kp, Vp, cfl, att16);
  dim3 gO(NTOK / 64, DMODEL / 128);
  gemm_bt<1><<<gO, 256, 0, stream>>>(att16, wo16, NTOK, DMODEL, DMODEL, bo, features, nullptr, acc1, nullptr);
  ln_kernel<<<dim3(NTOK), 256, 0, stream>>>(acc1, ln1g, ln1b, nullptr, x16);
  gemm_bt<2><<<dim3(NTOK / 64, DFFN / 128), 256, 0, stream>>>(x16, w116, NTOK, DFFN, DMODEL, b1, nullptr, nullptr, nullptr, h16);
  gemm_bt<3><<<gO, 256, 0, stream>>>(h16, w216, NTOK, DMODEL, DFFN, b2, nullptr, x16, acc1, nullptr);
  ln_kernel<<<dim3(NTOK), 256, 0, stream>>>(acc1, ln2g, ln2b, outp, nullptr);
}